// Round 6
// baseline (671.381 us; speedup 1.0000x reference)
//
#include <hip/hip_runtime.h>

#define VSZ 32000
#define DSZ 256
#define BSZ 32
#define MSZ 1024
#define PSZ 1025
#define VD  (VSZ * DSZ)
#define NBLK 256

// Workspace layout (float offsets)
#define OFF_U     32768                 // after int pos[M*B]
#define OFF_U0    40960
#define OFF_PP    57344                 // [B][PSZ] = 32800
#define OFF_GIH   90144                 // [1536][B] = 49152
#define OFF_SC    139296                // [M][B] = 32768
#define OFF_W     172064                // [V][B] = 1024000
#define OFF_PMAX  1196064               // [128][B]
#define OFF_PSUM  1200160               // [128][B]
#define OFF_PROJ  1204256               // [B][V] = 1024000
#define OFF_BAR   2228256               // barrier zone (32 uints), memset each call

// Output layout (floats): prob_lg [B,M] | p_vocab [B,V] | hidden [1,B,D]
#define OUT_PV  (BSZ * MSZ)
#define OUT_HID (OUT_PV + BSZ * VSZ)

// ---------------------------------------------------------------------------
// Software grid barrier: device-scope atomics (Guideline 16). cnt at bar[0],
// gen at bar[16] (separate 64B lines). lg is each thread's local generation.
__device__ __forceinline__ void gbar(unsigned* cnt, unsigned* gen, unsigned& lg) {
    __syncthreads();
    if (threadIdx.x == 0) {
        unsigned a = __hip_atomic_fetch_add(cnt, 1u, __ATOMIC_ACQ_REL,
                                            __HIP_MEMORY_SCOPE_AGENT);
        if (a == NBLK - 1) {
            __hip_atomic_store(cnt, 0u, __ATOMIC_RELAXED, __HIP_MEMORY_SCOPE_AGENT);
            __hip_atomic_store(gen, lg + 1u, __ATOMIC_RELEASE, __HIP_MEMORY_SCOPE_AGENT);
        } else {
            while (__hip_atomic_load(gen, __ATOMIC_ACQUIRE,
                                     __HIP_MEMORY_SCOPE_AGENT) <= lg)
                __builtin_amdgcn_s_sleep(1);
        }
    }
    lg += 1u;
    __syncthreads();
}

// ---------------------------------------------------------------------------
// Row-per-lane streamer: dest[r*drow + (b0+j)*dcol] = W[r]·x[b0+j] (+bias)
template <int COLS>
__device__ __forceinline__ void stream_rows(
    const float* __restrict__ W, const float* __restrict__ xS,
    float* __restrict__ dest, const float* __restrict__ bias,
    size_t drow, size_t dcol, int rbeg, int rend, int t)
{
    int lane = t & 63, b0 = (t >> 6) * 8;
    for (int r = rbeg + lane; r < rend; r += 64) {
        const float* wp = W + (size_t)r * COLS;
        float acc[8] = {0.f, 0.f, 0.f, 0.f, 0.f, 0.f, 0.f, 0.f};
        float4 wa[4], na[4];
#pragma unroll
        for (int k = 0; k < 4; ++k) wa[k] = *(const float4*)(wp + k * 4);
        constexpr int NS = COLS / 16;
        for (int s = 0; s < NS; ++s) {
            if (s < NS - 1) {
#pragma unroll
                for (int k = 0; k < 4; ++k)
                    na[k] = *(const float4*)(wp + (s + 1) * 16 + k * 4);
            }
            const float* xb = xS + (size_t)b0 * COLS + s * 16;
#pragma unroll
            for (int j = 0; j < 8; ++j) {
                const float* xp = xb + (size_t)j * COLS;
#pragma unroll
                for (int k = 0; k < 4; ++k) {
                    float4 xv = *(const float4*)(xp + k * 4);
                    acc[j] += wa[k].x * xv.x + wa[k].y * xv.y +
                              wa[k].z * xv.z + wa[k].w * xv.w;
                }
            }
#pragma unroll
            for (int k = 0; k < 4; ++k) wa[k] = na[k];
        }
        float bv = bias ? bias[r] : 0.f;
#pragma unroll
        for (int j = 0; j < 8; ++j)
            dest[(size_t)r * drow + (size_t)(b0 + j) * dcol] = acc[j] + bv;
    }
}

// okgemm: u[(b0+j)*D + lane*4..] += sum_{v in [vb,ve)} w[v][b0+j] * Ct[v][:]
__device__ __forceinline__ void okgemm_atomic(
    const float* __restrict__ Ct, const float* __restrict__ wv,
    float* __restrict__ u, int vb, int ve, int t)
{
    int lane = t & 63, b0 = (t >> 6) * 8;
    float4 acc[8];
#pragma unroll
    for (int j = 0; j < 8; ++j) acc[j] = make_float4(0.f, 0.f, 0.f, 0.f);
    float4 cv = ((const float4*)(Ct + (size_t)vb * DSZ))[lane];
    float4 w0 = *(const float4*)&wv[(size_t)vb * BSZ + b0];
    float4 w1 = *(const float4*)&wv[(size_t)vb * BSZ + b0 + 4];
    for (int v = vb; v < ve; ++v) {
        float4 c = cv, a = w0, q = w1;
        if (v + 1 < ve) {
            cv = ((const float4*)(Ct + (size_t)(v + 1) * DSZ))[lane];
            w0 = *(const float4*)&wv[(size_t)(v + 1) * BSZ + b0];
            w1 = *(const float4*)&wv[(size_t)(v + 1) * BSZ + b0 + 4];
        }
        acc[0].x += a.x * c.x; acc[0].y += a.x * c.y; acc[0].z += a.x * c.z; acc[0].w += a.x * c.w;
        acc[1].x += a.y * c.x; acc[1].y += a.y * c.y; acc[1].z += a.y * c.z; acc[1].w += a.y * c.w;
        acc[2].x += a.z * c.x; acc[2].y += a.z * c.y; acc[2].z += a.z * c.z; acc[2].w += a.z * c.w;
        acc[3].x += a.w * c.x; acc[3].y += a.w * c.y; acc[3].z += a.w * c.z; acc[3].w += a.w * c.w;
        acc[4].x += q.x * c.x; acc[4].y += q.x * c.y; acc[4].z += q.x * c.z; acc[4].w += q.x * c.w;
        acc[5].x += q.y * c.x; acc[5].y += q.y * c.y; acc[5].z += q.y * c.z; acc[5].w += q.y * c.w;
        acc[6].x += q.z * c.x; acc[6].y += q.z * c.y; acc[6].z += q.z * c.z; acc[6].w += q.z * c.w;
        acc[7].x += q.w * c.x; acc[7].y += q.w * c.y; acc[7].z += q.w * c.z; acc[7].w += q.w * c.w;
    }
#pragma unroll
    for (int j = 0; j < 8; ++j) {
        float* dst = &u[(size_t)(b0 + j) * DSZ + lane * 4];
        atomicAdd(dst + 0, acc[j].x);
        atomicAdd(dst + 1, acc[j].y);
        atomicAdd(dst + 2, acc[j].z);
        atomicAdd(dst + 3, acc[j].w);
    }
}

// ---------------------------------------------------------------------------
__global__ __launch_bounds__(256) void k_main(
    const int* __restrict__ story, const int* __restrict__ encq,
    const float* __restrict__ lasth, const float* __restrict__ C,
    const float* __restrict__ postab, const float* __restrict__ W1w,
    const float* __restrict__ W1b, const float* __restrict__ gwih,
    const float* __restrict__ gwhh, const float* __restrict__ gbih,
    const float* __restrict__ gbhh, float* __restrict__ out,
    float* __restrict__ wsf)
{
    const int gid = blockIdx.x, t = threadIdx.x;
    const int lane = t & 63, wid = t >> 6;

    int*   pos  = (int*)wsf;
    float* u    = wsf + OFF_U;
    float* u0   = wsf + OFF_U0;
    float* pp   = wsf + OFF_PP;
    float* gih  = wsf + OFF_GIH;
    float* sc   = wsf + OFF_SC;
    float* w    = wsf + OFF_W;
    float* pmax = wsf + OFF_PMAX;
    float* psum = wsf + OFF_PSUM;
    float* proj = wsf + OFF_PROJ;
    unsigned* cnt = (unsigned*)(wsf + OFF_BAR);
    unsigned* gen = (unsigned*)(wsf + OFF_BAR + 16);
    unsigned lg = 0;

    __shared__ float xS[BSZ * 512];          // 64 KB total; red/wtot aliased in
    float* const red = xS;                   // 256 floats
    int* const wtot = (int*)(xS + 260);      // 4 ints

    // ---- P0: positions (blocks 0..31)  ||  GRU MV (blocks 32..55) ----------
    if (gid < 32) {
        int b = gid, m0 = t * 4;
        int f0 = story[(size_t)((m0 + 0) * BSZ + b) * 4] != 0;
        int f1 = story[(size_t)((m0 + 1) * BSZ + b) * 4] != 0;
        int f2 = story[(size_t)((m0 + 2) * BSZ + b) * 4] != 0;
        int f3 = story[(size_t)((m0 + 3) * BSZ + b) * 4] != 0;
        int p1 = f0 + f1, p2 = p1 + f2, p3 = p2 + f3;
        int x = p3;
        for (int o = 1; o < 64; o <<= 1) {
            int v = __shfl_up(x, o, 64);
            if (lane >= o) x += v;
        }
        if (lane == 63) wtot[wid] = x;
        __syncthreads();
        int wo = 0;
        for (int i = 0; i < wid; ++i) wo += wtot[i];
        int base = wo + x - p3;
        pos[(m0 + 0) * BSZ + b] = f0 ? base + f0 : 0;
        pos[(m0 + 1) * BSZ + b] = f1 ? base + p1 : 0;
        pos[(m0 + 2) * BSZ + b] = f2 ? base + p2 : 0;
        pos[(m0 + 3) * BSZ + b] = f3 ? base + p3 : 0;
    } else if (gid < 56) {
        int k = gid - 32;
        bool isX = (k < 12);
        for (int i = t; i < BSZ * 64; i += 256) {
            int b = i >> 6, c4 = i & 63;
            float4 v = isX ? ((const float4*)(C + (size_t)encq[b] * DSZ))[c4]
                           : ((const float4*)(lasth + (size_t)b * DSZ))[c4];
            *(float4*)&xS[(size_t)(b << 8) + c4 * 4] = v;
        }
        __syncthreads();
        int kr = isX ? k : k - 12;
        const float* W = isX ? gwih : gwhh;
        float* dest = gih + (isX ? 0 : 768 * BSZ);
        stream_rows<256>(W, xS, dest, nullptr, BSZ, 1, kr * 64, kr * 64 + 64, t);
    }
    gbar(cnt, gen, lg);

    // ---- P1: GRU finalize (blocks 0..31) -----------------------------------
    if (gid < 32) {
        int idx = gid * 256 + t;
        int b = idx & 31, d = idx >> 5;
        float gi0 = gih[(size_t)(0 * DSZ + d) * BSZ + b] + gbih[0 * DSZ + d];
        float gi1 = gih[(size_t)(1 * DSZ + d) * BSZ + b] + gbih[1 * DSZ + d];
        float gi2 = gih[(size_t)(2 * DSZ + d) * BSZ + b] + gbih[2 * DSZ + d];
        float gh0 = gih[(size_t)(3 * DSZ + d) * BSZ + b] + gbhh[0 * DSZ + d];
        float gh1 = gih[(size_t)(4 * DSZ + d) * BSZ + b] + gbhh[1 * DSZ + d];
        float gh2 = gih[(size_t)(5 * DSZ + d) * BSZ + b] + gbhh[2 * DSZ + d];
        float r = 1.f / (1.f + __expf(-(gi0 + gh0)));
        float z = 1.f / (1.f + __expf(-(gi1 + gh1)));
        float n = tanhf(gi2 + r * gh2);
        float h = lasth[(size_t)b * DSZ + d];
        float hn = (1.f - z) * n + z * h;
        int o = b * DSZ + d;
        u[o] = hn; u0[o] = hn; out[OUT_HID + o] = hn;
    }
    gbar(cnt, gen, lg);

    // ---- P2: posproj (blocks 0..16) || proj hop0 (blocks 17..255) ----------
    {
        for (int i = t; i < BSZ * 64; i += 256) {
            int b = i >> 6, c4 = i & 63;
            *(float4*)&xS[(size_t)(b << 8) + c4 * 4] = ((const float4*)u)[(b << 6) + c4];
        }
        __syncthreads();
        if (gid < 17) {
            int rb = gid * 64, re = min(rb + 64, PSZ);
            stream_rows<256>(postab, xS, pp, nullptr, 1, PSZ, rb, re, t);
        } else {
            int i = gid - 17;
            int rb = i * 134, re = min(rb + 134, VSZ);
            stream_rows<256>(C, xS, proj, nullptr, 1, VSZ, rb, re, t);
        }
    }
    gbar(cnt, gen, lg);

    // ---- hop loop ----------------------------------------------------------
    for (int hop = 0; hop < 3; ++hop) {
        // scores (+block softmax stats) on 0..127 ; zero w on 128..255
        if (gid < 128) {
            int idx = gid * 256 + t;
            int b = idx & 31, m = idx >> 5;
            int4 st = *(const int4*)&story[(size_t)idx * 4];
            const float* pb = proj + (size_t)b * VSZ;
            float s = pb[st.x] + pb[st.y] + pb[st.z] + pb[st.w];
            if (hop == 0) s += pp[(size_t)b * PSZ + pos[idx]];
            if (hop == 2) {
                out[b * MSZ + m] = s;
            } else {
                sc[idx] = s;
                red[t] = s;
                __syncthreads();
                if (t < 32) {
                    float mx = red[t];
#pragma unroll
                    for (int k = 1; k < 8; ++k) mx = fmaxf(mx, red[k * 32 + t]);
                    float sm = 0.f;
#pragma unroll
                    for (int k = 0; k < 8; ++k) sm += __expf(red[k * 32 + t] - mx);
                    pmax[gid * 32 + t] = mx;
                    psum[gid * 32 + t] = sm;
                }
            }
        } else if (hop < 2) {
            float4 z4 = make_float4(0.f, 0.f, 0.f, 0.f);
            float4* w4 = (float4*)w;
            for (int i = (gid - 128) * 256 + t; i < VSZ * BSZ / 4; i += 128 * 256)
                w4[i] = z4;
        }
        if (hop == 2) break;
        gbar(cnt, gen, lg);

        // scatter: 256 blocks = (b, mc); combine 128 partial stats, atomicAdd
        {
            int b = gid >> 3, mc = gid & 7;
            red[t] = (t < 128) ? pmax[t * 32 + b] : -3.4e38f;
            __syncthreads();
            for (int o = 128; o >= 1; o >>= 1) {
                if (t < o) red[t] = fmaxf(red[t], red[t + o]);
                __syncthreads();
            }
            float M = red[0];
            __syncthreads();
            red[t] = (t < 128) ? psum[t * 32 + b] * __expf(pmax[t * 32 + b] - M) : 0.f;
            __syncthreads();
            for (int o = 128; o >= 1; o >>= 1) {
                if (t < o) red[t] += red[t + o];
                __syncthreads();
            }
            float S = red[0];
            if (t < 128) {
                int m = mc * 128 + t;
                float p = __expf(sc[m * BSZ + b] - M) / S;
                int4 st = *(const int4*)&story[(size_t)(m * BSZ + b) * 4];
                atomicAdd(&w[(size_t)st.x * BSZ + b], p);
                atomicAdd(&w[(size_t)st.y * BSZ + b], p);
                atomicAdd(&w[(size_t)st.z * BSZ + b], p);
                atomicAdd(&w[(size_t)st.w * BSZ + b], p);
            }
        }
        gbar(cnt, gen, lg);

        // okgemm over C[hop+1]: 256 blocks x 125 rows, atomicAdd into u
        okgemm_atomic(C + (size_t)(hop + 1) * VD, w, u,
                      gid * 125, gid * 125 + 125, t);
        gbar(cnt, gen, lg);

        // tail: hop0 -> proj h1 (84 blk) || pvocab (172 blk); hop1 -> proj h2
        if (hop == 0) {
            if (gid < 84) {
                for (int i = t; i < BSZ * 64; i += 256) {
                    int b = i >> 6, c4 = i & 63;
                    *(float4*)&xS[(size_t)(b << 8) + c4 * 4] =
                        ((const float4*)u)[(b << 6) + c4];
                }
                __syncthreads();
                int rb = gid * 381, re = min(rb + 381, VSZ);
                stream_rows<256>(C + (size_t)VD, xS, proj, nullptr, 1, VSZ, rb, re, t);
            } else {
                for (int i = t; i < BSZ * 128; i += 256) {
                    int b = i >> 7, c4 = i & 127;
                    float4 v;
                    if (c4 < 64) {
                        v = ((const float4*)u0)[(b << 6) + c4];
                    } else {
                        float4 a = ((const float4*)u)[(b << 6) + (c4 - 64)];
                        float4 c = ((const float4*)u0)[(b << 6) + (c4 - 64)];
                        v = make_float4(a.x - c.x, a.y - c.y, a.z - c.z, a.w - c.w);
                    }
                    *(float4*)&xS[(size_t)(b << 9) + c4 * 4] = v;
                }
                __syncthreads();
                int i = gid - 84;
                int rb = i * 187, re = min(rb + 187, VSZ);
                stream_rows<512>(W1w, xS, out + OUT_PV, W1b, 1, VSZ, rb, re, t);
            }
        } else {
            for (int i = t; i < BSZ * 64; i += 256) {
                int b = i >> 6, c4 = i & 63;
                *(float4*)&xS[(size_t)(b << 8) + c4 * 4] =
                    ((const float4*)u)[(b << 6) + c4];
            }
            __syncthreads();
            int rb = gid * 125, re = rb + 125;
            stream_rows<256>(C + (size_t)2 * VD, xS, proj, nullptr, 1, VSZ, rb, re, t);
        }
        gbar(cnt, gen, lg);
    }
}

// ---------------------------------------------------------------------------
extern "C" void kernel_launch(void* const* d_in, const int* in_sizes, int n_in,
                              void* d_out, int out_size, void* d_ws, size_t ws_size,
                              hipStream_t stream) {
    const int*   story  = (const int*)d_in[0];
    const int*   encq   = (const int*)d_in[1];
    const float* lasth  = (const float*)d_in[2];
    const float* C      = (const float*)d_in[3];
    const float* postab = (const float*)d_in[4];
    const float* W1w    = (const float*)d_in[5];
    const float* W1b    = (const float*)d_in[6];
    const float* gwih   = (const float*)d_in[7];
    const float* gwhh   = (const float*)d_in[8];
    const float* gbih   = (const float*)d_in[9];
    const float* gbhh   = (const float*)d_in[10];
    float* out = (float*)d_out;
    float* wsf = (float*)d_ws;

    // zero the barrier zone (capture-safe), then one persistent kernel
    hipMemsetAsync(wsf + OFF_BAR, 0, 128, stream);
    k_main<<<NBLK, 256, 0, stream>>>(story, encq, lasth, C, postab, W1w, W1b,
                                     gwih, gwhh, gbih, gbhh, out, wsf);
}

// Round 7
// 501.709 us; speedup vs baseline: 1.3382x; 1.3382x over previous
//
#include <hip/hip_runtime.h>

#define VSZ 32000
#define DSZ 256
#define BSZ 32
#define MSZ 1024
#define PSZ 1025
#define VD  (VSZ * DSZ)
#define NBLK 256

// Workspace layout (float offsets)
#define OFF_U     32768                 // after int pos[M*B]
#define OFF_U0    40960
#define OFF_PP    57344                 // [B][PSZ] = 32800
#define OFF_GIH   90144                 // [1536][B] = 49152
#define OFF_SC    139296                // [M][B] = 32768
#define OFF_W     172064                // [V][B] = 1024000
#define OFF_PMAX  1196064               // [128][B]
#define OFF_PSUM  1200160               // [128][B]
#define OFF_PROJ  1204256               // [B][V] = 1024000
#define OFF_BAR   2228256               // barrier zone (32 uints), memset each call

// Output layout (floats): prob_lg [B,M] | p_vocab [B,V] | hidden [1,B,D]
#define OUT_PV  (BSZ * MSZ)
#define OUT_HID (OUT_PV + BSZ * VSZ)

// ---------------------------------------------------------------------------
// Software grid barrier. Arrival: fetch_add ACQ_REL (release = L2 writeback,
// once per block). Spin: RELAXED polls (no buffer_inv storm — the R6 killer).
// Exit: one ACQUIRE load (single L2 invalidate per block per barrier).
__device__ __forceinline__ void gbar(unsigned* cnt, unsigned* gen, unsigned& lg) {
    __syncthreads();
    if (threadIdx.x == 0) {
        unsigned a = __hip_atomic_fetch_add(cnt, 1u, __ATOMIC_ACQ_REL,
                                            __HIP_MEMORY_SCOPE_AGENT);
        if (a == NBLK - 1) {
            __hip_atomic_store(cnt, 0u, __ATOMIC_RELAXED, __HIP_MEMORY_SCOPE_AGENT);
            __hip_atomic_store(gen, lg + 1u, __ATOMIC_RELEASE, __HIP_MEMORY_SCOPE_AGENT);
        } else {
            while (__hip_atomic_load(gen, __ATOMIC_RELAXED,
                                     __HIP_MEMORY_SCOPE_AGENT) <= lg)
                __builtin_amdgcn_s_sleep(4);
            (void)__hip_atomic_load(gen, __ATOMIC_ACQUIRE, __HIP_MEMORY_SCOPE_AGENT);
        }
    }
    lg += 1u;
    __syncthreads();
}

// ---------------------------------------------------------------------------
// 2-row x 32-col-step streamer: dest[r*drow+(b0+j)*dcol] = W[r]·x[b0+j] (+bias)
// 128 B/lane prefetch in flight; x read from LDS (wave-uniform = broadcast).
template <int COLS>
__device__ __forceinline__ void stream2(
    const float* __restrict__ W, const float* __restrict__ xS,
    float* __restrict__ dest, const float* __restrict__ bias,
    size_t drow, size_t dcol, int rbeg, int rend, int t)
{
    const int lane = t & 63, b0 = (t >> 6) * 8;
    constexpr int NS = COLS / 32;
    int r = rbeg + lane;
    for (; r + 64 < rend; r += 128) {
        const float* w0p = W + (size_t)r * COLS;
        const float* w1p = W + (size_t)(r + 64) * COLS;
        float acc0[8] = {}, acc1[8] = {};
        float4 ca[8], cb[8], na[8], nb[8];
#pragma unroll
        for (int k = 0; k < 8; ++k) {
            ca[k] = *(const float4*)(w0p + k * 4);
            cb[k] = *(const float4*)(w1p + k * 4);
        }
        for (int s = 0; s < NS; ++s) {
            if (s + 1 < NS) {
#pragma unroll
                for (int k = 0; k < 8; ++k) {
                    na[k] = *(const float4*)(w0p + (s + 1) * 32 + k * 4);
                    nb[k] = *(const float4*)(w1p + (s + 1) * 32 + k * 4);
                }
            }
            const float* xb = xS + (size_t)b0 * COLS + s * 32;
#pragma unroll
            for (int j = 0; j < 8; ++j) {
                const float* xp = xb + (size_t)j * COLS;
#pragma unroll
                for (int k = 0; k < 8; ++k) {
                    float4 xv = *(const float4*)(xp + k * 4);
                    acc0[j] += ca[k].x * xv.x + ca[k].y * xv.y +
                               ca[k].z * xv.z + ca[k].w * xv.w;
                    acc1[j] += cb[k].x * xv.x + cb[k].y * xv.y +
                               cb[k].z * xv.z + cb[k].w * xv.w;
                }
            }
#pragma unroll
            for (int k = 0; k < 8; ++k) { ca[k] = na[k]; cb[k] = nb[k]; }
        }
        float bv0 = bias ? bias[r] : 0.f;
        float bv1 = bias ? bias[r + 64] : 0.f;
#pragma unroll
        for (int j = 0; j < 8; ++j) {
            dest[(size_t)r * drow + (size_t)(b0 + j) * dcol] = acc0[j] + bv0;
            dest[(size_t)(r + 64) * drow + (size_t)(b0 + j) * dcol] = acc1[j] + bv1;
        }
    }
    // single-row tail (16-col steps)
    for (; r < rend; r += 64) {
        const float* wp = W + (size_t)r * COLS;
        float acc[8] = {};
        float4 wa[4], na2[4];
#pragma unroll
        for (int k = 0; k < 4; ++k) wa[k] = *(const float4*)(wp + k * 4);
        constexpr int NS2 = COLS / 16;
        for (int s = 0; s < NS2; ++s) {
            if (s + 1 < NS2) {
#pragma unroll
                for (int k = 0; k < 4; ++k)
                    na2[k] = *(const float4*)(wp + (s + 1) * 16 + k * 4);
            }
            const float* xb = xS + (size_t)b0 * COLS + s * 16;
#pragma unroll
            for (int j = 0; j < 8; ++j) {
                const float* xp = xb + (size_t)j * COLS;
#pragma unroll
                for (int k = 0; k < 4; ++k) {
                    float4 xv = *(const float4*)(xp + k * 4);
                    acc[j] += wa[k].x * xv.x + wa[k].y * xv.y +
                              wa[k].z * xv.z + wa[k].w * xv.w;
                }
            }
#pragma unroll
            for (int k = 0; k < 4; ++k) wa[k] = na2[k];
        }
        float bv = bias ? bias[r] : 0.f;
#pragma unroll
        for (int j = 0; j < 8; ++j)
            dest[(size_t)r * drow + (size_t)(b0 + j) * dcol] = acc[j] + bv;
    }
}

// ---------------------------------------------------------------------------
// ok rank-update, 8-deep pipelined: u[(b0+j)*D+...] += sum_v w[v][b0+j]*Ct[v][:]
// 128 rows per block.
__device__ __forceinline__ void okgemm8(
    const float* __restrict__ Ct, const float* __restrict__ wv,
    float* __restrict__ u, int vb, int t)
{
    const int lane = t & 63, b0 = (t >> 6) * 8;
    float4 acc[8];
#pragma unroll
    for (int j = 0; j < 8; ++j) acc[j] = make_float4(0.f, 0.f, 0.f, 0.f);
    float4 cv[8], w0[8], w1[8];
#pragma unroll
    for (int k = 0; k < 8; ++k) {
        cv[k] = ((const float4*)(Ct + (size_t)(vb + k) * DSZ))[lane];
        w0[k] = *(const float4*)&wv[(size_t)(vb + k) * BSZ + b0];
        w1[k] = *(const float4*)&wv[(size_t)(vb + k) * BSZ + b0 + 4];
    }
    for (int base = 0; base < 128; base += 8) {
        const bool pf = (base + 8 < 128);
#pragma unroll
        for (int k = 0; k < 8; ++k) {
            float4 c = cv[k], A = w0[k], Q = w1[k];
            if (pf) {
                int vn = vb + base + k + 8;
                cv[k] = ((const float4*)(Ct + (size_t)vn * DSZ))[lane];
                w0[k] = *(const float4*)&wv[(size_t)vn * BSZ + b0];
                w1[k] = *(const float4*)&wv[(size_t)vn * BSZ + b0 + 4];
            }
            acc[0].x += A.x * c.x; acc[0].y += A.x * c.y; acc[0].z += A.x * c.z; acc[0].w += A.x * c.w;
            acc[1].x += A.y * c.x; acc[1].y += A.y * c.y; acc[1].z += A.y * c.z; acc[1].w += A.y * c.w;
            acc[2].x += A.z * c.x; acc[2].y += A.z * c.y; acc[2].z += A.z * c.z; acc[2].w += A.z * c.w;
            acc[3].x += A.w * c.x; acc[3].y += A.w * c.y; acc[3].z += A.w * c.z; acc[3].w += A.w * c.w;
            acc[4].x += Q.x * c.x; acc[4].y += Q.x * c.y; acc[4].z += Q.x * c.z; acc[4].w += Q.x * c.w;
            acc[5].x += Q.y * c.x; acc[5].y += Q.y * c.y; acc[5].z += Q.y * c.z; acc[5].w += Q.y * c.w;
            acc[6].x += Q.z * c.x; acc[6].y += Q.z * c.y; acc[6].z += Q.z * c.z; acc[6].w += Q.z * c.w;
            acc[7].x += Q.w * c.x; acc[7].y += Q.w * c.y; acc[7].z += Q.w * c.z; acc[7].w += Q.w * c.w;
        }
    }
#pragma unroll
    for (int j = 0; j < 8; ++j) {
        float* dst = &u[(size_t)(b0 + j) * DSZ + lane * 4];
        atomicAdd(dst + 0, acc[j].x);
        atomicAdd(dst + 1, acc[j].y);
        atomicAdd(dst + 2, acc[j].z);
        atomicAdd(dst + 3, acc[j].w);
    }
}

// ---------------------------------------------------------------------------
__global__ __launch_bounds__(256, 1) void k_main(
    const int* __restrict__ story, const int* __restrict__ encq,
    const float* __restrict__ lasth, const float* __restrict__ C,
    const float* __restrict__ postab, const float* __restrict__ W1w,
    const float* __restrict__ W1b, const float* __restrict__ gwih,
    const float* __restrict__ gwhh, const float* __restrict__ gbih,
    const float* __restrict__ gbhh, float* __restrict__ out,
    float* __restrict__ wsf)
{
    const int gid = blockIdx.x, t = threadIdx.x;
    const int lane = t & 63, wid = t >> 6;

    int*   pos  = (int*)wsf;
    float* u    = wsf + OFF_U;
    float* u0   = wsf + OFF_U0;
    float* pp   = wsf + OFF_PP;
    float* gih  = wsf + OFF_GIH;
    float* sc   = wsf + OFF_SC;
    float* w    = wsf + OFF_W;
    float* pmax = wsf + OFF_PMAX;
    float* psum = wsf + OFF_PSUM;
    float* proj = wsf + OFF_PROJ;
    unsigned* cnt = (unsigned*)(wsf + OFF_BAR);
    unsigned* gen = (unsigned*)(wsf + OFF_BAR + 16);
    unsigned lg = 0;

    __shared__ float xS[BSZ * 512];          // 64 KB; red/wtot aliased in
    float* const red = xS;                   // 256 floats
    int* const wtot = (int*)(xS + 260);      // 4 ints

    // ---- P0: positions (blocks 0..31)  ||  GRU MV (blocks 32..43) ----------
    if (gid < 32) {
        int b = gid, m0 = t * 4;
        int f0 = story[(size_t)((m0 + 0) * BSZ + b) * 4] != 0;
        int f1 = story[(size_t)((m0 + 1) * BSZ + b) * 4] != 0;
        int f2 = story[(size_t)((m0 + 2) * BSZ + b) * 4] != 0;
        int f3 = story[(size_t)((m0 + 3) * BSZ + b) * 4] != 0;
        int p1 = f0 + f1, p2 = p1 + f2, p3 = p2 + f3;
        int x = p3;
        for (int o = 1; o < 64; o <<= 1) {
            int v = __shfl_up(x, o, 64);
            if (lane >= o) x += v;
        }
        if (lane == 63) wtot[wid] = x;
        __syncthreads();
        int wo = 0;
        for (int i = 0; i < wid; ++i) wo += wtot[i];
        int base = wo + x - p3;
        pos[(m0 + 0) * BSZ + b] = f0 ? base + f0 : 0;
        pos[(m0 + 1) * BSZ + b] = f1 ? base + p1 : 0;
        pos[(m0 + 2) * BSZ + b] = f2 ? base + p2 : 0;
        pos[(m0 + 3) * BSZ + b] = f3 ? base + p3 : 0;
    } else if (gid < 44) {
        int k = gid - 32;
        bool isX = (k < 6);
        for (int i = t; i < BSZ * 64; i += 256) {
            int b = i >> 6, c4 = i & 63;
            float4 v = isX ? ((const float4*)(C + (size_t)encq[b] * DSZ))[c4]
                           : ((const float4*)(lasth + (size_t)b * DSZ))[c4];
            *(float4*)&xS[(size_t)(b << 8) + c4 * 4] = v;
        }
        __syncthreads();
        int kr = isX ? k : k - 6;
        const float* W = isX ? gwih : gwhh;
        float* dest = gih + (isX ? 0 : 768 * BSZ);
        stream2<256>(W, xS, dest, nullptr, BSZ, 1, kr * 128, kr * 128 + 128, t);
    }
    gbar(cnt, gen, lg);

    // ---- P1: GRU finalize (blocks 0..31) -----------------------------------
    if (gid < 32) {
        int idx = gid * 256 + t;
        int b = idx & 31, d = idx >> 5;
        float gi0 = gih[(size_t)(0 * DSZ + d) * BSZ + b] + gbih[0 * DSZ + d];
        float gi1 = gih[(size_t)(1 * DSZ + d) * BSZ + b] + gbih[1 * DSZ + d];
        float gi2 = gih[(size_t)(2 * DSZ + d) * BSZ + b] + gbih[2 * DSZ + d];
        float gh0 = gih[(size_t)(3 * DSZ + d) * BSZ + b] + gbhh[0 * DSZ + d];
        float gh1 = gih[(size_t)(4 * DSZ + d) * BSZ + b] + gbhh[1 * DSZ + d];
        float gh2 = gih[(size_t)(5 * DSZ + d) * BSZ + b] + gbhh[2 * DSZ + d];
        float r = 1.f / (1.f + __expf(-(gi0 + gh0)));
        float z = 1.f / (1.f + __expf(-(gi1 + gh1)));
        float n = tanhf(gi2 + r * gh2);
        float h = lasth[(size_t)b * DSZ + d];
        float hn = (1.f - z) * n + z * h;
        int o = b * DSZ + d;
        u[o] = hn; u0[o] = hn; out[OUT_HID + o] = hn;
    }
    gbar(cnt, gen, lg);

    // ---- P2: proj hop0 (blocks 0..249) || posproj (blocks 250..255) --------
    {
        for (int i = t; i < BSZ * 64; i += 256) {
            int b = i >> 6, c4 = i & 63;
            *(float4*)&xS[(size_t)(b << 8) + c4 * 4] = ((const float4*)u)[(b << 6) + c4];
        }
        __syncthreads();
        if (gid < 250) {
            stream2<256>(C, xS, proj, nullptr, 1, VSZ, gid * 128, gid * 128 + 128, t);
        } else {
            int i = gid - 250;
            int rb = i * 171, re = min(rb + 171, PSZ);
            stream2<256>(postab, xS, pp, nullptr, 1, PSZ, rb, re, t);
        }
    }
    gbar(cnt, gen, lg);

    // ---- hop loop ----------------------------------------------------------
    for (int hop = 0; hop < 3; ++hop) {
        // scores (+block softmax stats) on 0..127 ; zero w on 128..255
        if (gid < 128) {
            int idx = gid * 256 + t;
            int b = idx & 31, m = idx >> 5;
            int4 st = *(const int4*)&story[(size_t)idx * 4];
            const float* pb = proj + (size_t)b * VSZ;
            float s = pb[st.x] + pb[st.y] + pb[st.z] + pb[st.w];
            if (hop == 0) s += pp[(size_t)b * PSZ + pos[idx]];
            if (hop == 2) {
                out[b * MSZ + m] = s;
            } else {
                sc[idx] = s;
                red[t] = s;
                __syncthreads();
                if (t < 32) {
                    float mx = red[t];
#pragma unroll
                    for (int k = 1; k < 8; ++k) mx = fmaxf(mx, red[k * 32 + t]);
                    float sm = 0.f;
#pragma unroll
                    for (int k = 0; k < 8; ++k) sm += __expf(red[k * 32 + t] - mx);
                    pmax[gid * 32 + t] = mx;
                    psum[gid * 32 + t] = sm;
                }
            }
        } else if (hop < 2) {
            float4 z4 = make_float4(0.f, 0.f, 0.f, 0.f);
            float4* w4 = (float4*)w;
            for (int i = (gid - 128) * 256 + t; i < VSZ * BSZ / 4; i += 128 * 256)
                w4[i] = z4;
        }
        if (hop == 2) break;
        gbar(cnt, gen, lg);

        // scatter: 256 blocks = (b, mc); combine 128 partial stats, atomicAdd
        {
            int b = gid >> 3, mc = gid & 7;
            red[t] = (t < 128) ? pmax[t * 32 + b] : -3.4e38f;
            __syncthreads();
            for (int o = 128; o >= 1; o >>= 1) {
                if (t < o) red[t] = fmaxf(red[t], red[t + o]);
                __syncthreads();
            }
            float M = red[0];
            __syncthreads();
            red[t] = (t < 128) ? psum[t * 32 + b] * __expf(pmax[t * 32 + b] - M) : 0.f;
            __syncthreads();
            for (int o = 128; o >= 1; o >>= 1) {
                if (t < o) red[t] += red[t + o];
                __syncthreads();
            }
            float S = red[0];
            if (t < 128) {
                int m = mc * 128 + t;
                float p = __expf(sc[m * BSZ + b] - M) / S;
                int4 st = *(const int4*)&story[(size_t)(m * BSZ + b) * 4];
                atomicAdd(&w[(size_t)st.x * BSZ + b], p);
                atomicAdd(&w[(size_t)st.y * BSZ + b], p);
                atomicAdd(&w[(size_t)st.z * BSZ + b], p);
                atomicAdd(&w[(size_t)st.w * BSZ + b], p);
            }
        }
        gbar(cnt, gen, lg);

        // okgemm over C[hop+1]: 250 blocks x 128 rows, atomicAdd into u
        if (gid < 250)
            okgemm8(C + (size_t)(hop + 1) * VD, w, u, gid * 128, t);
        gbar(cnt, gen, lg);

        // tail: hop0 -> proj h1 (84 blk) || pvocab (172 blk); hop1 -> proj h2
        if (hop == 0) {
            if (gid < 84) {
                for (int i = t; i < BSZ * 64; i += 256) {
                    int b = i >> 6, c4 = i & 63;
                    *(float4*)&xS[(size_t)(b << 8) + c4 * 4] =
                        ((const float4*)u)[(b << 6) + c4];
                }
                __syncthreads();
                int rb = gid * 381, re = min(rb + 381, VSZ);
                stream2<256>(C + (size_t)VD, xS, proj, nullptr, 1, VSZ, rb, re, t);
            } else {
                for (int i = t; i < BSZ * 128; i += 256) {
                    int b = i >> 7, c4 = i & 127;
                    float4 v;
                    if (c4 < 64) {
                        v = ((const float4*)u0)[(b << 6) + c4];
                    } else {
                        float4 a = ((const float4*)u)[(b << 6) + (c4 - 64)];
                        float4 c = ((const float4*)u0)[(b << 6) + (c4 - 64)];
                        v = make_float4(a.x - c.x, a.y - c.y, a.z - c.z, a.w - c.w);
                    }
                    *(float4*)&xS[(size_t)(b << 9) + c4 * 4] = v;
                }
                __syncthreads();
                int i = gid - 84;
                int rb = i * 187, re = min(rb + 187, VSZ);
                stream2<512>(W1w, xS, out + OUT_PV, W1b, 1, VSZ, rb, re, t);
            }
        } else {
            for (int i = t; i < BSZ * 64; i += 256) {
                int b = i >> 6, c4 = i & 63;
                *(float4*)&xS[(size_t)(b << 8) + c4 * 4] =
                    ((const float4*)u)[(b << 6) + c4];
            }
            __syncthreads();
            stream2<256>(C + (size_t)2 * VD, xS, proj, nullptr, 1, VSZ,
                         gid * 125, gid * 125 + 125, t);
        }
        gbar(cnt, gen, lg);
    }
}

// ---------------------------------------------------------------------------
extern "C" void kernel_launch(void* const* d_in, const int* in_sizes, int n_in,
                              void* d_out, int out_size, void* d_ws, size_t ws_size,
                              hipStream_t stream) {
    const int*   story  = (const int*)d_in[0];
    const int*   encq   = (const int*)d_in[1];
    const float* lasth  = (const float*)d_in[2];
    const float* C      = (const float*)d_in[3];
    const float* postab = (const float*)d_in[4];
    const float* W1w    = (const float*)d_in[5];
    const float* W1b    = (const float*)d_in[6];
    const float* gwih   = (const float*)d_in[7];
    const float* gwhh   = (const float*)d_in[8];
    const float* gbih   = (const float*)d_in[9];
    const float* gbhh   = (const float*)d_in[10];
    float* out = (float*)d_out;
    float* wsf = (float*)d_ws;

    // zero the barrier zone (capture-safe), then one persistent kernel
    hipMemsetAsync(wsf + OFF_BAR, 0, 128, stream);
    k_main<<<NBLK, 256, 0, stream>>>(story, encq, lasth, C, postab, W1w, W1b,
                                     gwih, gwhh, gbih, gbhh, out, wsf);
}

// Round 8
// 383.021 us; speedup vs baseline: 1.7529x; 1.3099x over previous
//
#include <hip/hip_runtime.h>

#define VSZ 32000
#define DSZ 256
#define BSZ 32
#define MSZ 1024
#define PSZ 1025
#define VD  (VSZ * DSZ)

// Workspace layout (float offsets)
#define OFF_U     32768                 // after int pos[M*B]
#define OFF_U0    40960
#define OFF_PP    49152                 // [B][PSZ] = 32800
#define OFF_GIH   81952                 // [1536][B] = 49152
#define OFF_SC    131104                // [M][B] = 32768
#define OFF_PMAX  163872                // [128][B] = 4096
#define OFF_PSUM  167968                // [128][B] = 4096
#define OFF_PROJ  172064                // [B][V] = 1024000

// Output layout (floats): prob_lg [B,M] | p_vocab [B,V] | hidden [1,B,D]
#define OUT_PV  (BSZ * MSZ)
#define OUT_HID (OUT_PV + BSZ * VSZ)

// ---------------------------------------------------------------------------
// Single-row streamer, 32-col steps, 8 float4 in flight per lane.
// dest[r*drow + (b0+j)*dcol] = W[r]·x[b0+j] (+bias). x in LDS (wave-uniform
// reads = broadcast, conflict-free).
template <int COLS>
__device__ __forceinline__ void stream1(
    const float* __restrict__ W, const float* __restrict__ xS,
    float* __restrict__ dest, const float* __restrict__ bias,
    size_t drow, size_t dcol, int rbeg, int rend, int t)
{
    const int lane = t & 63, b0 = (t >> 6) * 8;
    constexpr int NS = COLS / 32;
    for (int r = rbeg + lane; r < rend; r += 64) {
        const float* wp = W + (size_t)r * COLS;
        float acc[8] = {};
        float4 ca[8], na[8];
#pragma unroll
        for (int k = 0; k < 8; ++k) ca[k] = *(const float4*)(wp + k * 4);
        for (int s = 0; s < NS; ++s) {
            if (s + 1 < NS) {
#pragma unroll
                for (int k = 0; k < 8; ++k)
                    na[k] = *(const float4*)(wp + (s + 1) * 32 + k * 4);
            }
            const float* xb = xS + (size_t)b0 * COLS + s * 32;
#pragma unroll
            for (int j = 0; j < 8; ++j) {
                const float* xp = xb + (size_t)j * COLS;
#pragma unroll
                for (int k = 0; k < 8; ++k) {
                    float4 xv = *(const float4*)(xp + k * 4);
                    acc[j] += ca[k].x * xv.x + ca[k].y * xv.y +
                              ca[k].z * xv.z + ca[k].w * xv.w;
                }
            }
#pragma unroll
            for (int k = 0; k < 8; ++k) ca[k] = na[k];
        }
        float bv = bias ? bias[r] : 0.f;
#pragma unroll
        for (int j = 0; j < 8; ++j)
            dest[(size_t)r * drow + (size_t)(b0 + j) * dcol] = acc[j] + bv;
    }
}

// ---------------------------------------------------------------------------
// K1: positions (blocks 0..31) || GRU matvec (blocks 32..43)
__global__ __launch_bounds__(256) void k_posgru(
    const int* __restrict__ story, const int* __restrict__ encq,
    const float* __restrict__ lasth, const float* __restrict__ C0,
    const float* __restrict__ gwih, const float* __restrict__ gwhh,
    int* __restrict__ pos, float* __restrict__ gih)
{
    int gid = blockIdx.x, t = threadIdx.x;
    int lane = t & 63, wid = t >> 6;
    if (gid < 32) {
        __shared__ int wtot[4];
        int b = gid, m0 = t * 4;
        int f0 = story[(size_t)((m0 + 0) * BSZ + b) * 4] != 0;
        int f1 = story[(size_t)((m0 + 1) * BSZ + b) * 4] != 0;
        int f2 = story[(size_t)((m0 + 2) * BSZ + b) * 4] != 0;
        int f3 = story[(size_t)((m0 + 3) * BSZ + b) * 4] != 0;
        int p1 = f0 + f1, p2 = p1 + f2, p3 = p2 + f3;
        int x = p3;
        for (int o = 1; o < 64; o <<= 1) {
            int v = __shfl_up(x, o, 64);
            if (lane >= o) x += v;
        }
        if (lane == 63) wtot[wid] = x;
        __syncthreads();
        int wo = 0;
        for (int i = 0; i < wid; ++i) wo += wtot[i];
        int base = wo + x - p3;
        pos[(m0 + 0) * BSZ + b] = f0 ? base + f0 : 0;
        pos[(m0 + 1) * BSZ + b] = f1 ? base + p1 : 0;
        pos[(m0 + 2) * BSZ + b] = f2 ? base + p2 : 0;
        pos[(m0 + 3) * BSZ + b] = f3 ? base + p3 : 0;
    } else if (gid < 44) {
        __shared__ float xS[BSZ * DSZ];
        int k = gid - 32;
        bool isX = (k < 6);
        for (int i = t; i < BSZ * 64; i += 256) {
            int b = i >> 6, c4 = i & 63;
            float4 v = isX ? ((const float4*)(C0 + (size_t)encq[b] * DSZ))[c4]
                           : ((const float4*)(lasth + (size_t)b * DSZ))[c4];
            *(float4*)&xS[(size_t)(b << 8) + c4 * 4] = v;
        }
        __syncthreads();
        int kr = isX ? k : k - 6;
        const float* W = isX ? gwih : gwhh;
        float* dest = gih + (isX ? 0 : 768 * BSZ);
        stream1<DSZ>(W, xS, dest, nullptr, BSZ, 1, kr * 128, kr * 128 + 128, t);
    }
}

// ---------------------------------------------------------------------------
// K2: GRU finalize. 32 x 256, idx = b + 32*d (coalesced gih reads).
__global__ void k_grufin(const float* __restrict__ gih,
                         const float* __restrict__ gbih, const float* __restrict__ gbhh,
                         const float* __restrict__ lasth,
                         float* __restrict__ u, float* __restrict__ u0,
                         float* __restrict__ hid)
{
    int idx = blockIdx.x * 256 + threadIdx.x;
    int b = idx & 31, d = idx >> 5;
    float gi0 = gih[(size_t)(0 * DSZ + d) * BSZ + b] + gbih[0 * DSZ + d];
    float gi1 = gih[(size_t)(1 * DSZ + d) * BSZ + b] + gbih[1 * DSZ + d];
    float gi2 = gih[(size_t)(2 * DSZ + d) * BSZ + b] + gbih[2 * DSZ + d];
    float gh0 = gih[(size_t)(3 * DSZ + d) * BSZ + b] + gbhh[0 * DSZ + d];
    float gh1 = gih[(size_t)(4 * DSZ + d) * BSZ + b] + gbhh[1 * DSZ + d];
    float gh2 = gih[(size_t)(5 * DSZ + d) * BSZ + b] + gbhh[2 * DSZ + d];
    float r = 1.f / (1.f + __expf(-(gi0 + gh0)));
    float z = 1.f / (1.f + __expf(-(gi1 + gh1)));
    float n = tanhf(gi2 + r * gh2);
    float h = lasth[(size_t)b * DSZ + d];
    float hn = (1.f - z) * n + z * h;
    int o = b * DSZ + d;
    u[o] = hn; u0[o] = hn; hid[o] = hn;
}

// ---------------------------------------------------------------------------
// K3/K7: proj stream (+ posproj on trailing blocks when pp != nullptr).
// proj[b][v] = C[h][v]·u[b]; pp[b][p] = postab[p]·u[b].
__global__ __launch_bounds__(256) void k_proj(
    const float* __restrict__ Ct, const float* __restrict__ postab,
    const float* __restrict__ u, float* __restrict__ proj,
    float* __restrict__ pp, int nproj, int rows)
{
    __shared__ float xS[BSZ * DSZ];
    int gid = blockIdx.x, t = threadIdx.x;
    for (int i = t; i < BSZ * 64; i += 256) {
        int b = i >> 6, c4 = i & 63;
        *(float4*)&xS[(size_t)(b << 8) + c4 * 4] = ((const float4*)u)[(b << 6) + c4];
    }
    __syncthreads();
    if (gid < nproj) {
        int rb = gid * rows, re = min(rb + rows, VSZ);
        stream1<DSZ>(Ct, xS, proj, nullptr, 1, VSZ, rb, re, t);
    } else {
        int i = gid - nproj;
        int rb = i * 171, re = min(rb + 171, PSZ);
        stream1<DSZ>(postab, xS, pp, nullptr, 1, PSZ, rb, re, t);
    }
}

// ---------------------------------------------------------------------------
// K4: scores (+ per-block softmax stats for hop<2; logits to out at hop 2).
// 128 blocks x 256; idx = m*32+b.
__global__ void k_scores(const int* __restrict__ story, const int* __restrict__ pos,
                         const float* __restrict__ proj, const float* __restrict__ pp,
                         float* __restrict__ sc, float* __restrict__ pmax,
                         float* __restrict__ psum, float* __restrict__ outlg, int hop)
{
    __shared__ float red[256];
    int gid = blockIdx.x, t = threadIdx.x;
    int idx = gid * 256 + t;
    int b = idx & 31, m = idx >> 5;
    int4 st = *(const int4*)&story[(size_t)idx * 4];
    const float* pb = proj + (size_t)b * VSZ;
    float s = pb[st.x] + pb[st.y] + pb[st.z] + pb[st.w];
    if (hop == 0) s += pp[(size_t)b * PSZ + pos[idx]];
    if (hop == 2) { outlg[b * MSZ + m] = s; return; }
    sc[idx] = s;
    red[t] = s;
    __syncthreads();
    if (t < 32) {
        float mx = red[t];
#pragma unroll
        for (int k = 1; k < 8; ++k) mx = fmaxf(mx, red[k * 32 + t]);
        float sm = 0.f;
#pragma unroll
        for (int k = 0; k < 8; ++k) sm += __expf(red[k * 32 + t] - mx);
        pmax[gid * 32 + t] = mx;
        psum[gid * 32 + t] = sm;
    }
}

// ---------------------------------------------------------------------------
// K5: gather-PV. 512 blocks = (16 mc x 32 b), 256 thr = 4 m-groups x 64 d-lanes.
// Combines softmax stats, computes p inline, gathers C rows, atomicAdds u.
__global__ __launch_bounds__(256) void k_okpv(
    const int* __restrict__ story, const float* __restrict__ sc,
    const float* __restrict__ pmax, const float* __restrict__ psum,
    const float* __restrict__ Ct, float* __restrict__ u)
{
    int b = blockIdx.x & 31, mc = blockIdx.x >> 5;
    int t = threadIdx.x;
    __shared__ float red[256];
    __shared__ float pl[64];
    __shared__ float4 pt[4][64];
    red[t] = (t < 128) ? pmax[t * 32 + b] : -3.4e38f;
    __syncthreads();
    for (int o = 128; o >= 1; o >>= 1) {
        if (t < o) red[t] = fmaxf(red[t], red[t + o]);
        __syncthreads();
    }
    float M = red[0];
    __syncthreads();
    red[t] = (t < 128) ? psum[t * 32 + b] * __expf(pmax[t * 32 + b] - M) : 0.f;
    __syncthreads();
    for (int o = 128; o >= 1; o >>= 1) {
        if (t < o) red[t] += red[t + o];
        __syncthreads();
    }
    float S = red[0];
    __syncthreads();
    if (t < 64) pl[t] = __expf(sc[(size_t)(mc * 64 + t) * BSZ + b] - M) / S;
    __syncthreads();
    int dl = t & 63, mg = t >> 6;
    int mbase = mc * 64 + mg * 16;
    float4 acc = make_float4(0.f, 0.f, 0.f, 0.f);
    int4 st = *(const int4*)&story[(size_t)(mbase * BSZ + b) * 4];
    float pw = pl[mg * 16];
#pragma unroll 4
    for (int i = 0; i < 16; ++i) {
        int4 s_ = st; float p_ = pw;
        if (i < 15) {
            st = *(const int4*)&story[(size_t)((mbase + i + 1) * BSZ + b) * 4];
            pw = pl[mg * 16 + i + 1];
        }
        float4 a0 = ((const float4*)(Ct + (size_t)s_.x * DSZ))[dl];
        float4 a1 = ((const float4*)(Ct + (size_t)s_.y * DSZ))[dl];
        float4 a2 = ((const float4*)(Ct + (size_t)s_.z * DSZ))[dl];
        float4 a3 = ((const float4*)(Ct + (size_t)s_.w * DSZ))[dl];
        acc.x += p_ * (a0.x + a1.x + a2.x + a3.x);
        acc.y += p_ * (a0.y + a1.y + a2.y + a3.y);
        acc.z += p_ * (a0.z + a1.z + a2.z + a3.z);
        acc.w += p_ * (a0.w + a1.w + a2.w + a3.w);
    }
    pt[mg][dl] = acc;
    __syncthreads();
    if (t < 64) {
        float4 s0 = pt[0][t], s1 = pt[1][t], s2 = pt[2][t], s3 = pt[3][t];
        float* dst = &u[(size_t)b * DSZ + t * 4];
        atomicAdd(dst + 0, s0.x + s1.x + s2.x + s3.x);
        atomicAdd(dst + 1, s0.y + s1.y + s2.y + s3.y);
        atomicAdd(dst + 2, s0.z + s1.z + s2.z + s3.z);
        atomicAdd(dst + 3, s0.w + s1.w + s2.w + s3.w);
    }
}

// ---------------------------------------------------------------------------
// K6: tail0 — proj hop1 (blocks 0..112) || pvocab (blocks 113..343).
__global__ __launch_bounds__(256) void k_tail0(
    const float* __restrict__ C1, const float* __restrict__ u,
    const float* __restrict__ u0, const float* __restrict__ W1w,
    const float* __restrict__ W1b, float* __restrict__ proj,
    float* __restrict__ out_pv)
{
    __shared__ float xS[BSZ * 512];
    int gid = blockIdx.x, t = threadIdx.x;
    if (gid < 113) {
        for (int i = t; i < BSZ * 64; i += 256) {
            int b = i >> 6, c4 = i & 63;
            *(float4*)&xS[(size_t)(b << 8) + c4 * 4] = ((const float4*)u)[(b << 6) + c4];
        }
        __syncthreads();
        int rb = gid * 284, re = min(rb + 284, VSZ);
        stream1<DSZ>(C1, xS, proj, nullptr, 1, VSZ, rb, re, t);
    } else {
        for (int i = t; i < BSZ * 128; i += 256) {
            int b = i >> 7, c4 = i & 127;
            float4 v;
            if (c4 < 64) {
                v = ((const float4*)u0)[(b << 6) + c4];
            } else {
                float4 a = ((const float4*)u)[(b << 6) + (c4 - 64)];
                float4 c = ((const float4*)u0)[(b << 6) + (c4 - 64)];
                v = make_float4(a.x - c.x, a.y - c.y, a.z - c.z, a.w - c.w);
            }
            *(float4*)&xS[(size_t)(b << 9) + c4 * 4] = v;
        }
        __syncthreads();
        int i = gid - 113;
        int rb = i * 139, re = min(rb + 139, VSZ);
        stream1<512>(W1w, xS, out_pv, W1b, 1, VSZ, rb, re, t);
    }
}

// ---------------------------------------------------------------------------
extern "C" void kernel_launch(void* const* d_in, const int* in_sizes, int n_in,
                              void* d_out, int out_size, void* d_ws, size_t ws_size,
                              hipStream_t stream) {
    const int*   story  = (const int*)d_in[0];
    const int*   encq   = (const int*)d_in[1];
    const float* lasth  = (const float*)d_in[2];
    const float* C      = (const float*)d_in[3];
    const float* postab = (const float*)d_in[4];
    const float* W1w    = (const float*)d_in[5];
    const float* W1b    = (const float*)d_in[6];
    const float* gwih   = (const float*)d_in[7];
    const float* gwhh   = (const float*)d_in[8];
    const float* gbih   = (const float*)d_in[9];
    const float* gbhh   = (const float*)d_in[10];

    float* out = (float*)d_out;
    float* wsf = (float*)d_ws;
    int*   pos  = (int*)d_ws;
    float* u    = wsf + OFF_U;
    float* u0   = wsf + OFF_U0;
    float* pp   = wsf + OFF_PP;
    float* gih  = wsf + OFF_GIH;
    float* sc   = wsf + OFF_SC;
    float* pmax = wsf + OFF_PMAX;
    float* psum = wsf + OFF_PSUM;
    float* proj = wsf + OFF_PROJ;

    k_posgru<<<44, 256, 0, stream>>>(story, encq, lasth, C, gwih, gwhh, pos, gih);
    k_grufin<<<32, 256, 0, stream>>>(gih, gbih, gbhh, lasth, u, u0, out + OUT_HID);
    // proj hop0 (500 blocks x 64 rows) + posproj (6 blocks)
    k_proj<<<506, 256, 0, stream>>>(C, postab, u, proj, pp, 500, 64);

    for (int hop = 0; hop < 3; ++hop) {
        k_scores<<<128, 256, 0, stream>>>(story, pos, proj, pp, sc, pmax, psum,
                                          out, hop);
        if (hop == 2) break;
        k_okpv<<<512, 256, 0, stream>>>(story, sc, pmax, psum,
                                        C + (size_t)(hop + 1) * VD, u);
        if (hop == 0) {
            k_tail0<<<344, 256, 0, stream>>>(C + (size_t)VD, u, u0, W1w, W1b,
                                             proj, out + OUT_PV);
        } else {
            k_proj<<<500, 256, 0, stream>>>(C + (size_t)2 * VD, nullptr, u, proj,
                                            nullptr, 500, 64);
        }
    }
}

// Round 9
// 238.362 us; speedup vs baseline: 2.8167x; 1.6069x over previous
//
#include <hip/hip_runtime.h>

#define VSZ 32000
#define DSZ 256
#define BSZ 32
#define MSZ 1024
#define PSZ 1025
#define VD  (VSZ * DSZ)

// Workspace layout (float offsets)
#define OFF_U     32768                 // after int pos[M*B]
#define OFF_U0    40960
#define OFF_PP    49152                 // [B][PSZ] = 32800
#define OFF_GIH   81952                 // [1536][B] = 49152
#define OFF_SC    131104                // [M][B] = 32768
#define OFF_PMAX  163872                // [128][B] = 4096
#define OFF_PSUM  167968                // [128][B] = 4096
#define OFF_PROJ  172064                // [B][V] = 1024000

// Output layout (floats): prob_lg [B,M] | p_vocab [B,V] | hidden [1,B,D]
#define OUT_PV  (BSZ * MSZ)
#define OUT_HID (OUT_PV + BSZ * VSZ)

// ---------------------------------------------------------------------------
// ROWS-per-lane streamer, 8-col steps. Each wave-uniform LDS x-read (16B,
// broadcast, ~12cyc return-bus) feeds ROWS*4 FMAs — ROWS=4 makes the VALU,
// not the LDS broadcast bus, the gate (R8 lesson: ROWS=1 was 3x LDS-bound).
template <int COLS, int ROWS>
__device__ __forceinline__ void streamN(
    const float* __restrict__ W, const float* __restrict__ xS,
    float* __restrict__ dest, const float* __restrict__ bias,
    size_t drow, size_t dcol, int rbeg, int rend, int t)
{
    const int lane = t & 63, b0 = (t >> 6) * 8;
    const int r0 = rbeg + lane;
    const float* wp[ROWS];
    bool valid[ROWS];
#pragma unroll
    for (int rr = 0; rr < ROWS; ++rr) {
        int r = r0 + rr * 64;
        valid[rr] = (r < rend);
        wp[rr] = W + (size_t)(valid[rr] ? r : (rend - 1)) * COLS;
    }
    float acc[ROWS][8] = {};
    float4 ca[ROWS][2], na[ROWS][2];
#pragma unroll
    for (int rr = 0; rr < ROWS; ++rr) {
        ca[rr][0] = *(const float4*)(wp[rr]);
        ca[rr][1] = *(const float4*)(wp[rr] + 4);
    }
    constexpr int NS = COLS / 8;
    for (int s = 0; s < NS; ++s) {
        if (s + 1 < NS) {
#pragma unroll
            for (int rr = 0; rr < ROWS; ++rr) {
                na[rr][0] = *(const float4*)(wp[rr] + (s + 1) * 8);
                na[rr][1] = *(const float4*)(wp[rr] + (s + 1) * 8 + 4);
            }
        }
        const float* xb = xS + (size_t)b0 * COLS + s * 8;
#pragma unroll
        for (int j = 0; j < 8; ++j) {
            float4 x0 = *(const float4*)(xb + (size_t)j * COLS);
            float4 x1 = *(const float4*)(xb + (size_t)j * COLS + 4);
#pragma unroll
            for (int rr = 0; rr < ROWS; ++rr) {
                acc[rr][j] += ca[rr][0].x * x0.x + ca[rr][0].y * x0.y +
                              ca[rr][0].z * x0.z + ca[rr][0].w * x0.w +
                              ca[rr][1].x * x1.x + ca[rr][1].y * x1.y +
                              ca[rr][1].z * x1.z + ca[rr][1].w * x1.w;
            }
        }
#pragma unroll
        for (int rr = 0; rr < ROWS; ++rr) {
            ca[rr][0] = na[rr][0];
            ca[rr][1] = na[rr][1];
        }
    }
#pragma unroll
    for (int rr = 0; rr < ROWS; ++rr) {
        if (valid[rr]) {
            int r = r0 + rr * 64;
            float bv = bias ? bias[r] : 0.f;
#pragma unroll
            for (int j = 0; j < 8; ++j)
                dest[(size_t)r * drow + (size_t)(b0 + j) * dcol] = acc[rr][j] + bv;
        }
    }
}

// ---------------------------------------------------------------------------
// K1: positions (blocks 0..31) || GRU matvec (blocks 32..37, 256 rows each)
__global__ __launch_bounds__(256) void k_posgru(
    const int* __restrict__ story, const int* __restrict__ encq,
    const float* __restrict__ lasth, const float* __restrict__ C0,
    const float* __restrict__ gwih, const float* __restrict__ gwhh,
    int* __restrict__ pos, float* __restrict__ gih)
{
    int gid = blockIdx.x, t = threadIdx.x;
    int lane = t & 63, wid = t >> 6;
    if (gid < 32) {
        __shared__ int wtot[4];
        int b = gid, m0 = t * 4;
        int f0 = story[(size_t)((m0 + 0) * BSZ + b) * 4] != 0;
        int f1 = story[(size_t)((m0 + 1) * BSZ + b) * 4] != 0;
        int f2 = story[(size_t)((m0 + 2) * BSZ + b) * 4] != 0;
        int f3 = story[(size_t)((m0 + 3) * BSZ + b) * 4] != 0;
        int p1 = f0 + f1, p2 = p1 + f2, p3 = p2 + f3;
        int x = p3;
        for (int o = 1; o < 64; o <<= 1) {
            int v = __shfl_up(x, o, 64);
            if (lane >= o) x += v;
        }
        if (lane == 63) wtot[wid] = x;
        __syncthreads();
        int wo = 0;
        for (int i = 0; i < wid; ++i) wo += wtot[i];
        int base = wo + x - p3;
        pos[(m0 + 0) * BSZ + b] = f0 ? base + f0 : 0;
        pos[(m0 + 1) * BSZ + b] = f1 ? base + p1 : 0;
        pos[(m0 + 2) * BSZ + b] = f2 ? base + p2 : 0;
        pos[(m0 + 3) * BSZ + b] = f3 ? base + p3 : 0;
    } else {
        __shared__ float xS[BSZ * DSZ];
        int k = gid - 32;              // 0..5
        bool isX = (k < 3);
        for (int i = t; i < BSZ * 64; i += 256) {
            int b = i >> 6, c4 = i & 63;
            float4 v = isX ? ((const float4*)(C0 + (size_t)encq[b] * DSZ))[c4]
                           : ((const float4*)(lasth + (size_t)b * DSZ))[c4];
            *(float4*)&xS[(size_t)(b << 8) + c4 * 4] = v;
        }
        __syncthreads();
        int kr = isX ? k : k - 3;
        const float* W = isX ? gwih : gwhh;
        float* dest = gih + (isX ? 0 : 768 * BSZ);
        streamN<DSZ, 4>(W, xS, dest, nullptr, BSZ, 1, kr * 256, kr * 256 + 256, t);
    }
}

// ---------------------------------------------------------------------------
// K2: GRU finalize. 32 x 256, idx = b + 32*d (coalesced gih reads).
__global__ void k_grufin(const float* __restrict__ gih,
                         const float* __restrict__ gbih, const float* __restrict__ gbhh,
                         const float* __restrict__ lasth,
                         float* __restrict__ u, float* __restrict__ u0,
                         float* __restrict__ hid)
{
    int idx = blockIdx.x * 256 + threadIdx.x;
    int b = idx & 31, d = idx >> 5;
    float gi0 = gih[(size_t)(0 * DSZ + d) * BSZ + b] + gbih[0 * DSZ + d];
    float gi1 = gih[(size_t)(1 * DSZ + d) * BSZ + b] + gbih[1 * DSZ + d];
    float gi2 = gih[(size_t)(2 * DSZ + d) * BSZ + b] + gbih[2 * DSZ + d];
    float gh0 = gih[(size_t)(3 * DSZ + d) * BSZ + b] + gbhh[0 * DSZ + d];
    float gh1 = gih[(size_t)(4 * DSZ + d) * BSZ + b] + gbhh[1 * DSZ + d];
    float gh2 = gih[(size_t)(5 * DSZ + d) * BSZ + b] + gbhh[2 * DSZ + d];
    float r = 1.f / (1.f + __expf(-(gi0 + gh0)));
    float z = 1.f / (1.f + __expf(-(gi1 + gh1)));
    float n = tanhf(gi2 + r * gh2);
    float h = lasth[(size_t)b * DSZ + d];
    float hn = (1.f - z) * n + z * h;
    int o = b * DSZ + d;
    u[o] = hn; u0[o] = hn; hid[o] = hn;
}

// ---------------------------------------------------------------------------
// K3/K7: proj (blocks 0..nproj-1, 256 rows each) + optional posproj tail.
// proj[b][v] = C[h][v]·u[b]; pp[b][p] = postab[p]·u[b].
__global__ __launch_bounds__(256) void k_proj(
    const float* __restrict__ Ct, const float* __restrict__ postab,
    const float* __restrict__ u, float* __restrict__ proj,
    float* __restrict__ pp, int nproj)
{
    __shared__ float xS[BSZ * DSZ];
    int gid = blockIdx.x, t = threadIdx.x;
    for (int i = t; i < BSZ * 64; i += 256) {
        int b = i >> 6, c4 = i & 63;
        *(float4*)&xS[(size_t)(b << 8) + c4 * 4] = ((const float4*)u)[(b << 6) + c4];
    }
    __syncthreads();
    if (gid < nproj) {
        streamN<DSZ, 4>(Ct, xS, proj, nullptr, 1, VSZ, gid * 256, gid * 256 + 256, t);
    } else {
        int i = gid - nproj;
        streamN<DSZ, 4>(postab, xS, pp, nullptr, 1, PSZ, i * 256,
                        min(i * 256 + 256, PSZ), t);
    }
}

// ---------------------------------------------------------------------------
// K4: scores (+ per-block softmax stats for hop<2; logits to out at hop 2).
// 128 blocks x 256; idx = m*32+b.
__global__ void k_scores(const int* __restrict__ story, const int* __restrict__ pos,
                         const float* __restrict__ proj, const float* __restrict__ pp,
                         float* __restrict__ sc, float* __restrict__ pmax,
                         float* __restrict__ psum, float* __restrict__ outlg, int hop)
{
    __shared__ float red[256];
    int gid = blockIdx.x, t = threadIdx.x;
    int idx = gid * 256 + t;
    int b = idx & 31, m = idx >> 5;
    int4 st = *(const int4*)&story[(size_t)idx * 4];
    const float* pb = proj + (size_t)b * VSZ;
    float s = pb[st.x] + pb[st.y] + pb[st.z] + pb[st.w];
    if (hop == 0) s += pp[(size_t)b * PSZ + pos[idx]];
    if (hop == 2) { outlg[b * MSZ + m] = s; return; }
    sc[idx] = s;
    red[t] = s;
    __syncthreads();
    if (t < 32) {
        float mx = red[t];
#pragma unroll
        for (int k = 1; k < 8; ++k) mx = fmaxf(mx, red[k * 32 + t]);
        float sm = 0.f;
#pragma unroll
        for (int k = 0; k < 8; ++k) sm += __expf(red[k * 32 + t] - mx);
        pmax[gid * 32 + t] = mx;
        psum[gid * 32 + t] = sm;
    }
}

// ---------------------------------------------------------------------------
// K5: gather-PV. 512 blocks = (16 mc x 32 b), 256 thr = 4 m-groups x 64 d-lanes.
__global__ __launch_bounds__(256) void k_okpv(
    const int* __restrict__ story, const float* __restrict__ sc,
    const float* __restrict__ pmax, const float* __restrict__ psum,
    const float* __restrict__ Ct, float* __restrict__ u)
{
    int b = blockIdx.x & 31, mc = blockIdx.x >> 5;
    int t = threadIdx.x;
    __shared__ float red[256];
    __shared__ float pl[64];
    __shared__ float4 pt[4][64];
    red[t] = (t < 128) ? pmax[t * 32 + b] : -3.4e38f;
    __syncthreads();
    for (int o = 128; o >= 1; o >>= 1) {
        if (t < o) red[t] = fmaxf(red[t], red[t + o]);
        __syncthreads();
    }
    float M = red[0];
    __syncthreads();
    red[t] = (t < 128) ? psum[t * 32 + b] * __expf(pmax[t * 32 + b] - M) : 0.f;
    __syncthreads();
    for (int o = 128; o >= 1; o >>= 1) {
        if (t < o) red[t] += red[t + o];
        __syncthreads();
    }
    float S = red[0];
    __syncthreads();
    if (t < 64) pl[t] = __expf(sc[(size_t)(mc * 64 + t) * BSZ + b] - M) / S;
    __syncthreads();
    int dl = t & 63, mg = t >> 6;
    int mbase = mc * 64 + mg * 16;
    float4 acc = make_float4(0.f, 0.f, 0.f, 0.f);
    int4 st = *(const int4*)&story[(size_t)(mbase * BSZ + b) * 4];
    float pw = pl[mg * 16];
#pragma unroll 4
    for (int i = 0; i < 16; ++i) {
        int4 s_ = st; float p_ = pw;
        if (i < 15) {
            st = *(const int4*)&story[(size_t)((mbase + i + 1) * BSZ + b) * 4];
            pw = pl[mg * 16 + i + 1];
        }
        float4 a0 = ((const float4*)(Ct + (size_t)s_.x * DSZ))[dl];
        float4 a1 = ((const float4*)(Ct + (size_t)s_.y * DSZ))[dl];
        float4 a2 = ((const float4*)(Ct + (size_t)s_.z * DSZ))[dl];
        float4 a3 = ((const float4*)(Ct + (size_t)s_.w * DSZ))[dl];
        acc.x += p_ * (a0.x + a1.x + a2.x + a3.x);
        acc.y += p_ * (a0.y + a1.y + a2.y + a3.y);
        acc.z += p_ * (a0.z + a1.z + a2.z + a3.z);
        acc.w += p_ * (a0.w + a1.w + a2.w + a3.w);
    }
    pt[mg][dl] = acc;
    __syncthreads();
    if (t < 64) {
        float4 s0 = pt[0][t], s1 = pt[1][t], s2 = pt[2][t], s3 = pt[3][t];
        float* dst = &u[(size_t)b * DSZ + t * 4];
        atomicAdd(dst + 0, s0.x + s1.x + s2.x + s3.x);
        atomicAdd(dst + 1, s0.y + s1.y + s2.y + s3.y);
        atomicAdd(dst + 2, s0.z + s1.z + s2.z + s3.z);
        atomicAdd(dst + 3, s0.w + s1.w + s2.w + s3.w);
    }
}

// ---------------------------------------------------------------------------
// K6: tail0 — pvocab (blocks 0..124) || proj hop1 (blocks 125..249).
__global__ __launch_bounds__(256) void k_tail0(
    const float* __restrict__ C1, const float* __restrict__ u,
    const float* __restrict__ u0, const float* __restrict__ W1w,
    const float* __restrict__ W1b, float* __restrict__ proj,
    float* __restrict__ out_pv)
{
    __shared__ float xS[BSZ * 512];
    int gid = blockIdx.x, t = threadIdx.x;
    if (gid < 125) {
        for (int i = t; i < BSZ * 128; i += 256) {
            int b = i >> 7, c4 = i & 127;
            float4 v;
            if (c4 < 64) {
                v = ((const float4*)u0)[(b << 6) + c4];
            } else {
                float4 a = ((const float4*)u)[(b << 6) + (c4 - 64)];
                float4 c = ((const float4*)u0)[(b << 6) + (c4 - 64)];
                v = make_float4(a.x - c.x, a.y - c.y, a.z - c.z, a.w - c.w);
            }
            *(float4*)&xS[(size_t)(b << 9) + c4 * 4] = v;
        }
        __syncthreads();
        streamN<512, 4>(W1w, xS, out_pv, W1b, 1, VSZ, gid * 256, gid * 256 + 256, t);
    } else {
        for (int i = t; i < BSZ * 64; i += 256) {
            int b = i >> 6, c4 = i & 63;
            *(float4*)&xS[(size_t)(b << 8) + c4 * 4] = ((const float4*)u)[(b << 6) + c4];
        }
        __syncthreads();
        int i = gid - 125;
        streamN<DSZ, 4>(C1, xS, proj, nullptr, 1, VSZ, i * 256, i * 256 + 256, t);
    }
}

// ---------------------------------------------------------------------------
extern "C" void kernel_launch(void* const* d_in, const int* in_sizes, int n_in,
                              void* d_out, int out_size, void* d_ws, size_t ws_size,
                              hipStream_t stream) {
    const int*   story  = (const int*)d_in[0];
    const int*   encq   = (const int*)d_in[1];
    const float* lasth  = (const float*)d_in[2];
    const float* C      = (const float*)d_in[3];
    const float* postab = (const float*)d_in[4];
    const float* W1w    = (const float*)d_in[5];
    const float* W1b    = (const float*)d_in[6];
    const float* gwih   = (const float*)d_in[7];
    const float* gwhh   = (const float*)d_in[8];
    const float* gbih   = (const float*)d_in[9];
    const float* gbhh   = (const float*)d_in[10];

    float* out = (float*)d_out;
    float* wsf = (float*)d_ws;
    int*   pos  = (int*)d_ws;
    float* u    = wsf + OFF_U;
    float* u0   = wsf + OFF_U0;
    float* pp   = wsf + OFF_PP;
    float* gih  = wsf + OFF_GIH;
    float* sc   = wsf + OFF_SC;
    float* pmax = wsf + OFF_PMAX;
    float* psum = wsf + OFF_PSUM;
    float* proj = wsf + OFF_PROJ;

    k_posgru<<<38, 256, 0, stream>>>(story, encq, lasth, C, gwih, gwhh, pos, gih);
    k_grufin<<<32, 256, 0, stream>>>(gih, gbih, gbhh, lasth, u, u0, out + OUT_HID);
    // proj hop0 (125 blocks x 256 rows) + posproj (5 blocks)
    k_proj<<<130, 256, 0, stream>>>(C, postab, u, proj, pp, 125);

    for (int hop = 0; hop < 3; ++hop) {
        k_scores<<<128, 256, 0, stream>>>(story, pos, proj, pp, sc, pmax, psum,
                                          out, hop);
        if (hop == 2) break;
        k_okpv<<<512, 256, 0, stream>>>(story, sc, pmax, psum,
                                        C + (size_t)(hop + 1) * VD, u);
        if (hop == 0) {
            k_tail0<<<250, 256, 0, stream>>>(C + (size_t)VD, u, u0, W1w, W1b,
                                             proj, out + OUT_PV);
        } else {
            k_proj<<<125, 256, 0, stream>>>(C + (size_t)2 * VD, nullptr, u, proj,
                                            nullptr, 125);
        }
    }
}